// Round 1
// baseline (2275.135 us; speedup 1.0000x reference)
//
#include <hip/hip_runtime.h>

#define NN 100000      // nodes
#define NE 1200000     // edges
#define FIN 22
#define HD 64
#define NC 6
#define BN_EPS 1e-5f

// ---------------- degree / dinv ----------------
__global__ void k_deg_init(float* __restrict__ deg) {
    int i = blockIdx.x * blockDim.x + threadIdx.x;
    if (i < NN) deg[i] = 1.0f;   // self-loop
}

__global__ void k_deg_count(const int* __restrict__ dst, float* __restrict__ deg) {
    int e = blockIdx.x * blockDim.x + threadIdx.x;
    if (e < NE) atomicAdd(&deg[dst[e]], 1.0f);
}

__global__ void k_dinv(float* __restrict__ deg) {
    int i = blockIdx.x * blockDim.x + threadIdx.x;
    if (i < NN) deg[i] = rsqrtf(deg[i]);
}

// ---------------- embed: h = relu(x @ W_emb + b_emb) ----------------
// block = 256 threads = 4 nodes x 64 features
__global__ void k_embed(const float* __restrict__ x, const float* __restrict__ W,
                        const float* __restrict__ b, float* __restrict__ h) {
    __shared__ float Ws[FIN * HD];     // 22*64 = 1408 floats
    __shared__ float xs[4][FIN];
    int t = threadIdx.x;
    for (int i = t; i < FIN * HD; i += 256) Ws[i] = W[i];
    int n0 = blockIdx.x * 4;
    for (int i = t; i < 4 * FIN; i += 256) {
        int n = n0 + i / FIN;
        xs[i / FIN][i % FIN] = (n < NN) ? x[(long)n * FIN + i % FIN] : 0.f;
    }
    __syncthreads();
    int local = t >> 6;
    int f = t & 63;
    int n = n0 + local;
    if (n < NN) {
        float acc = b[f];
#pragma unroll
        for (int k = 0; k < FIN; ++k) acc = fmaf(xs[local][k], Ws[k * HD + f], acc);
        h[(long)n * HD + f] = fmaxf(acc, 0.f);
    }
}

// ---------------- layer GEMM: hw = hin @ W ; agg = hw * dinv^2 ----------------
// agg may alias hin: each block stages its own rows to LDS before writing.
__global__ void k_gemm_h(const float* __restrict__ hin, const float* __restrict__ W,
                         const float* __restrict__ dinv, float* __restrict__ hw,
                         float* __restrict__ agg) {
    __shared__ float Ws[HD * HD];      // 16 KB
    __shared__ float hs[4][HD];
    int t = threadIdx.x;
    for (int i = t; i < HD * HD; i += 256) Ws[i] = W[i];
    int n0 = blockIdx.x * 4;
    for (int i = t; i < 4 * HD; i += 256) {
        int n = n0 + (i >> 6);
        hs[i >> 6][i & 63] = (n < NN) ? hin[(long)n * HD + (i & 63)] : 0.f;
    }
    __syncthreads();
    int local = t >> 6;
    int f = t & 63;
    int n = n0 + local;
    if (n < NN) {
        float acc = 0.f;
#pragma unroll
        for (int k = 0; k < HD; ++k) acc = fmaf(hs[local][k], Ws[k * HD + f], acc);
        float di = dinv[n];
        hw[(long)n * HD + f] = acc;
        agg[(long)n * HD + f] = acc * di * di;
    }
}

// ---------------- edge scatter: agg[dst] += hw[src] * dinv[src]*dinv[dst] ----------------
// 16 threads per edge, 4 features each (float4 gather, 4 atomics)
__global__ void k_scatter(const int* __restrict__ src, const int* __restrict__ dst,
                          const float* __restrict__ dinv, const float* __restrict__ hw,
                          float* __restrict__ agg) {
    long gid = (long)blockIdx.x * blockDim.x + threadIdx.x;
    int e = (int)(gid >> 4);
    if (e >= NE) return;
    int f4 = ((int)gid & 15) * 4;
    int s = src[e], d = dst[e];
    float coef = dinv[s] * dinv[d];
    float4 v = *reinterpret_cast<const float4*>(&hw[(long)s * HD + f4]);
    float* ap = &agg[(long)d * HD + f4];
    atomicAdd(ap + 0, v.x * coef);
    atomicAdd(ap + 1, v.y * coef);
    atomicAdd(ap + 2, v.z * coef);
    atomicAdd(ap + 3, v.w * coef);
}

// ---------------- fused bias + BN(eval) + ReLU, in-place capable ----------------
__global__ void k_bnrelu(const float* __restrict__ agg, const float* __restrict__ bias,
                         const float* __restrict__ g, const float* __restrict__ be,
                         const float* __restrict__ m, const float* __restrict__ v,
                         float* __restrict__ out) {
    int i = blockIdx.x * blockDim.x + threadIdx.x;   // one float4 per thread
    if (i >= NN * HD / 4) return;
    int i4 = i * 4;
    int f = i4 & 63;
    float4 a = *reinterpret_cast<const float4*>(&agg[i4]);
    float r[4] = {a.x, a.y, a.z, a.w};
#pragma unroll
    for (int j = 0; j < 4; ++j) {
        int ff = f + j;
        float scale = g[ff] * rsqrtf(v[ff] + BN_EPS);
        float val = (r[j] + bias[ff] - m[ff]) * scale + be[ff];
        r[j] = fmaxf(val, 0.f);
    }
    float4 o = {r[0], r[1], r[2], r[3]};
    *reinterpret_cast<float4*>(&out[i4]) = o;
}

// ---------------- classifier: out = h @ W_cls + b_cls ----------------
__global__ void k_cls(const float* __restrict__ h, const float* __restrict__ W,
                      const float* __restrict__ b, float* __restrict__ out) {
    __shared__ float Ws[HD * NC];
    __shared__ float bs[NC];
    int t = threadIdx.x;
    for (int i = t; i < HD * NC; i += 256) Ws[i] = W[i];
    if (t < NC) bs[t] = b[t];
    __syncthreads();
    int n = blockIdx.x * 256 + t;
    if (n >= NN) return;
    float acc[NC];
#pragma unroll
    for (int c = 0; c < NC; ++c) acc[c] = bs[c];
    const float4* hp = reinterpret_cast<const float4*>(&h[(long)n * HD]);
#pragma unroll
    for (int k4 = 0; k4 < HD / 4; ++k4) {
        float4 hv = hp[k4];
        float hh[4] = {hv.x, hv.y, hv.z, hv.w};
#pragma unroll
        for (int j = 0; j < 4; ++j) {
            int k = k4 * 4 + j;
#pragma unroll
            for (int c = 0; c < NC; ++c) acc[c] = fmaf(hh[j], Ws[k * NC + c], acc[c]);
        }
    }
#pragma unroll
    for (int c = 0; c < NC; ++c) out[(long)n * NC + c] = acc[c];
}

extern "C" void kernel_launch(void* const* d_in, const int* in_sizes, int n_in,
                              void* d_out, int out_size, void* d_ws, size_t ws_size,
                              hipStream_t stream) {
    const float* x     = (const float*)d_in[0];
    const int*   ei    = (const int*)d_in[1];
    const float* W_emb = (const float*)d_in[2];
    const float* b_emb = (const float*)d_in[3];
    const float* W1    = (const float*)d_in[4];
    const float* b1    = (const float*)d_in[5];
    const float* g1    = (const float*)d_in[6];
    const float* be1   = (const float*)d_in[7];
    const float* m1    = (const float*)d_in[8];
    const float* v1    = (const float*)d_in[9];
    const float* W2    = (const float*)d_in[10];
    const float* b2    = (const float*)d_in[11];
    const float* g2    = (const float*)d_in[12];
    const float* be2   = (const float*)d_in[13];
    const float* m2    = (const float*)d_in[14];
    const float* v2    = (const float*)d_in[15];
    const float* W_cls = (const float*)d_in[16];
    const float* b_cls = (const float*)d_in[17];
    float* out = (float*)d_out;

    const int* src = ei;          // edge_index[0]
    const int* dst = ei + NE;     // edge_index[1]

    // workspace layout: dinv[N] | bufA[N*H] | bufB[N*H]
    float* dinv = (float*)d_ws;
    float* bufA = dinv + ((NN + 255) & ~255);
    float* bufB = bufA + (long)NN * HD;

    // degree -> dinv
    k_deg_init<<<(NN + 255) / 256, 256, 0, stream>>>(dinv);
    k_deg_count<<<(NE + 255) / 256, 256, 0, stream>>>(dst, dinv);
    k_dinv<<<(NN + 255) / 256, 256, 0, stream>>>(dinv);

    // embed
    k_embed<<<(NN + 3) / 4, 256, 0, stream>>>(x, W_emb, b_emb, bufA);

    // layer 1: gemm (bufA->bufB, agg init into bufA), scatter, bn+relu (in place bufA)
    k_gemm_h<<<(NN + 3) / 4, 256, 0, stream>>>(bufA, W1, dinv, bufB, bufA);
    k_scatter<<<(NE * 16 + 255) / 256, 256, 0, stream>>>(src, dst, dinv, bufB, bufA);
    k_bnrelu<<<(NN * HD / 4 + 255) / 256, 256, 0, stream>>>(bufA, b1, g1, be1, m1, v1, bufA);

    // layer 2
    k_gemm_h<<<(NN + 3) / 4, 256, 0, stream>>>(bufA, W2, dinv, bufB, bufA);
    k_scatter<<<(NE * 16 + 255) / 256, 256, 0, stream>>>(src, dst, dinv, bufB, bufA);
    k_bnrelu<<<(NN * HD / 4 + 255) / 256, 256, 0, stream>>>(bufA, b2, g2, be2, m2, v2, bufA);

    // classifier
    k_cls<<<(NN + 255) / 256, 256, 0, stream>>>(bufA, W_cls, b_cls, out);
}

// Round 2
// 512.931 us; speedup vs baseline: 4.4356x; 4.4356x over previous
//
#include <hip/hip_runtime.h>

#define NN 100000      // nodes
#define NE 1200000     // edges
#define FIN 22
#define HD 64
#define NC 6
#define BN_EPS 1e-5f
#define SCAN_B 256
#define SCAN_NB ((NN + SCAN_B - 1) / SCAN_B)   // 391

struct Entry { int s; float c; };   // src node, edge coefficient

// ---------------- CSR build ----------------
__global__ void k_zero_cnt(int* __restrict__ cnt) {
    int i = blockIdx.x * blockDim.x + threadIdx.x;
    if (i < NN) cnt[i] = 0;
}

__global__ void k_hist(const int* __restrict__ dst, int* __restrict__ cnt) {
    int e = blockIdx.x * blockDim.x + threadIdx.x;
    if (e < NE) atomicAdd(&cnt[dst[e]], 1);
}

__global__ void k_dinv(const int* __restrict__ cnt, float* __restrict__ dinv) {
    int i = blockIdx.x * blockDim.x + threadIdx.x;
    if (i < NN) dinv[i] = rsqrtf((float)cnt[i] + 1.0f);  // +1 self loop
}

// exclusive scan, level 1: per-block scan of cnt -> row_ptr, block totals -> partials
__global__ void k_scan1(const int* __restrict__ cnt, int* __restrict__ row_ptr,
                        int* __restrict__ partials) {
    __shared__ int s[SCAN_B];
    int t = threadIdx.x;
    int i = blockIdx.x * SCAN_B + t;
    int v = (i < NN) ? cnt[i] : 0;
    s[t] = v;
    __syncthreads();
    for (int off = 1; off < SCAN_B; off <<= 1) {
        int x = (t >= off) ? s[t - off] : 0;
        __syncthreads();
        s[t] += x;
        __syncthreads();
    }
    if (i < NN) row_ptr[i] = s[t] - v;                 // exclusive
    if (t == SCAN_B - 1) partials[blockIdx.x] = s[t];  // block total
}

// level 2: single block scans the partials (exclusive)
__global__ void k_scan2(int* __restrict__ partials) {
    __shared__ int s[512];
    int t = threadIdx.x;
    int v = (t < SCAN_NB) ? partials[t] : 0;
    s[t] = v;
    __syncthreads();
    for (int off = 1; off < 512; off <<= 1) {
        int x = (t >= off) ? s[t - off] : 0;
        __syncthreads();
        s[t] += x;
        __syncthreads();
    }
    if (t < SCAN_NB) partials[t] = s[t] - v;           // exclusive
}

// level 3: add block offsets; init cursor = row_ptr; cap row_ptr[N] = E
__global__ void k_scan3(int* __restrict__ row_ptr, int* __restrict__ cursor,
                        const int* __restrict__ partials) {
    int i = blockIdx.x * SCAN_B + threadIdx.x;
    if (i < NN) {
        int v = row_ptr[i] + partials[blockIdx.x];
        row_ptr[i] = v;
        cursor[i] = v;
    }
    if (i == 0) row_ptr[NN] = NE;
}

__global__ void k_fill(const int* __restrict__ src, const int* __restrict__ dst,
                       const float* __restrict__ dinv, int* __restrict__ cursor,
                       Entry* __restrict__ entries) {
    int e = blockIdx.x * blockDim.x + threadIdx.x;
    if (e >= NE) return;
    int s = src[e], d = dst[e];
    int p = atomicAdd(&cursor[d], 1);
    Entry en;
    en.s = s;
    en.c = dinv[s] * dinv[d];
    entries[p] = en;
}

// ---------------- embed: h = relu(x @ W_emb + b_emb) ----------------
__global__ void k_embed(const float* __restrict__ x, const float* __restrict__ W,
                        const float* __restrict__ b, float* __restrict__ h) {
    __shared__ float Ws[FIN * HD];
    __shared__ float xs[4][FIN];
    int t = threadIdx.x;
    for (int i = t; i < FIN * HD; i += 256) Ws[i] = W[i];
    int n0 = blockIdx.x * 4;
    for (int i = t; i < 4 * FIN; i += 256) {
        int n = n0 + i / FIN;
        xs[i / FIN][i % FIN] = (n < NN) ? x[(long)n * FIN + i % FIN] : 0.f;
    }
    __syncthreads();
    int local = t >> 6;
    int f = t & 63;
    int n = n0 + local;
    if (n < NN) {
        float acc = b[f];
#pragma unroll
        for (int k = 0; k < FIN; ++k) acc = fmaf(xs[local][k], Ws[k * HD + f], acc);
        h[(long)n * HD + f] = fmaxf(acc, 0.f);
    }
}

// ---------------- layer GEMM: hw = hin @ W ----------------
__global__ void k_gemm(const float* __restrict__ hin, const float* __restrict__ W,
                       float* __restrict__ hw) {
    __shared__ float Ws[HD * HD];      // 16 KB
    __shared__ float hs[4][HD];
    int t = threadIdx.x;
    for (int i = t; i < HD * HD; i += 256) Ws[i] = W[i];
    int n0 = blockIdx.x * 4;
    for (int i = t; i < 4 * HD; i += 256) {
        int n = n0 + (i >> 6);
        hs[i >> 6][i & 63] = (n < NN) ? hin[(long)n * HD + (i & 63)] : 0.f;
    }
    __syncthreads();
    int local = t >> 6;
    int f = t & 63;
    int n = n0 + local;
    if (n < NN) {
        float acc = 0.f;
#pragma unroll
        for (int k = 0; k < HD; ++k) acc = fmaf(hs[local][k], Ws[k * HD + f], acc);
        hw[(long)n * HD + f] = acc;
    }
}

// ---------------- fused gather + self-loop + bias + BN + ReLU ----------------
// one 64-lane wave per node (lane = feature), 4 nodes per block
__global__ void k_gather_bn(const float* __restrict__ hw, const float* __restrict__ dinv,
                            const int* __restrict__ row_ptr, const Entry* __restrict__ entries,
                            const float* __restrict__ bias, const float* __restrict__ g,
                            const float* __restrict__ be, const float* __restrict__ m,
                            const float* __restrict__ v, float* __restrict__ out) {
    int t = threadIdx.x;
    int n = blockIdx.x * 4 + (t >> 6);
    int f = t & 63;
    if (n >= NN) return;
    float di = dinv[n];
    float acc = hw[(long)n * HD + f] * di * di;        // self-loop term
    int b0 = row_ptr[n], b1 = row_ptr[n + 1];
    for (int e = b0; e < b1; ++e) {
        Entry en = entries[e];                         // wave-uniform load
        acc += hw[(long)en.s * HD + f] * en.c;         // coalesced 256B row gather
    }
    float scale = g[f] * rsqrtf(v[f] + BN_EPS);
    float val = (acc + bias[f] - m[f]) * scale + be[f];
    out[(long)n * HD + f] = fmaxf(val, 0.f);
}

// ---------------- classifier: out = h @ W_cls + b_cls ----------------
__global__ void k_cls(const float* __restrict__ h, const float* __restrict__ W,
                      const float* __restrict__ b, float* __restrict__ out) {
    __shared__ float Ws[HD * NC];
    __shared__ float bs[NC];
    int t = threadIdx.x;
    for (int i = t; i < HD * NC; i += 256) Ws[i] = W[i];
    if (t < NC) bs[t] = b[t];
    __syncthreads();
    int n = blockIdx.x * 256 + t;
    if (n >= NN) return;
    float acc[NC];
#pragma unroll
    for (int c = 0; c < NC; ++c) acc[c] = bs[c];
    const float4* hp = reinterpret_cast<const float4*>(&h[(long)n * HD]);
#pragma unroll
    for (int k4 = 0; k4 < HD / 4; ++k4) {
        float4 hv = hp[k4];
        float hh[4] = {hv.x, hv.y, hv.z, hv.w};
#pragma unroll
        for (int j = 0; j < 4; ++j) {
            int k = k4 * 4 + j;
#pragma unroll
            for (int c = 0; c < NC; ++c) acc[c] = fmaf(hh[j], Ws[k * NC + c], acc[c]);
        }
    }
#pragma unroll
    for (int c = 0; c < NC; ++c) out[(long)n * NC + c] = acc[c];
}

extern "C" void kernel_launch(void* const* d_in, const int* in_sizes, int n_in,
                              void* d_out, int out_size, void* d_ws, size_t ws_size,
                              hipStream_t stream) {
    const float* x     = (const float*)d_in[0];
    const int*   ei    = (const int*)d_in[1];
    const float* W_emb = (const float*)d_in[2];
    const float* b_emb = (const float*)d_in[3];
    const float* W1    = (const float*)d_in[4];
    const float* b1    = (const float*)d_in[5];
    const float* g1    = (const float*)d_in[6];
    const float* be1   = (const float*)d_in[7];
    const float* m1    = (const float*)d_in[8];
    const float* v1    = (const float*)d_in[9];
    const float* W2    = (const float*)d_in[10];
    const float* b2    = (const float*)d_in[11];
    const float* g2    = (const float*)d_in[12];
    const float* be2   = (const float*)d_in[13];
    const float* m2    = (const float*)d_in[14];
    const float* v2    = (const float*)d_in[15];
    const float* W_cls = (const float*)d_in[16];
    const float* b_cls = (const float*)d_in[17];
    float* out = (float*)d_out;

    const int* src = ei;          // edge_index[0]
    const int* dst = ei + NE;     // edge_index[1]

    // workspace layout (floats/ints are 4B; NP = padded N)
    const long NP = (NN + 511) & ~511;            // 100352
    float* dinv    = (float*)d_ws;                // NP
    int*   cnt     = (int*)(dinv + NP);           // NP (cnt, later cursor)
    int*   row_ptr = cnt + NP;                    // NP (needs N+1)
    int*   partials= row_ptr + NP;                // 1024
    Entry* entries = (Entry*)(partials + 1024);   // NE * 8B
    float* bufA    = (float*)(entries + NE);      // N*H
    float* bufB    = bufA + (long)NN * HD;        // N*H

    // ---- CSR build (once, shared by both layers) ----
    k_zero_cnt<<<SCAN_NB, SCAN_B, 0, stream>>>(cnt);
    k_hist<<<(NE + 255) / 256, 256, 0, stream>>>(dst, cnt);
    k_dinv<<<SCAN_NB, SCAN_B, 0, stream>>>(cnt, dinv);
    k_scan1<<<SCAN_NB, SCAN_B, 0, stream>>>(cnt, row_ptr, partials);
    k_scan2<<<1, 512, 0, stream>>>(partials);
    k_scan3<<<SCAN_NB, SCAN_B, 0, stream>>>(row_ptr, cnt /*cursor*/, partials);
    k_fill<<<(NE + 255) / 256, 256, 0, stream>>>(src, dst, dinv, cnt /*cursor*/, entries);

    // ---- pipeline ----
    k_embed<<<(NN + 3) / 4, 256, 0, stream>>>(x, W_emb, b_emb, bufA);

    k_gemm<<<(NN + 3) / 4, 256, 0, stream>>>(bufA, W1, bufB);
    k_gather_bn<<<(NN + 3) / 4, 256, 0, stream>>>(bufB, dinv, row_ptr, entries,
                                                  b1, g1, be1, m1, v1, bufA);

    k_gemm<<<(NN + 3) / 4, 256, 0, stream>>>(bufA, W2, bufB);
    k_gather_bn<<<(NN + 3) / 4, 256, 0, stream>>>(bufB, dinv, row_ptr, entries,
                                                  b2, g2, be2, m2, v2, bufA);

    k_cls<<<(NN + 255) / 256, 256, 0, stream>>>(bufA, W_cls, b_cls, out);
}